// Round 1
// baseline (553.433 us; speedup 1.0000x reference)
//
#include <hip/hip_runtime.h>
#include <math.h>

constexpr int B_ = 8;
constexpr int N_ = 16384;
constexpr int C_ = 128;    // input channels
constexpr int K_ = 16;     // neighbors
constexpr int CO = 256;    // output channels
constexpr int TC = 256;    // 2*C
constexpr int M_ = B_ * N_;        // 131072 rows
constexpr int TM = 64;             // nodes per block
constexpr int BK = 32;             // k-chunk
constexpr int LDH = TC + 4;        // padded h row (260): breaks tm-stride bank aliasing

__device__ __forceinline__ float4 f4max(float4 a, float4 b) {
  return make_float4(fmaxf(a.x, b.x), fmaxf(a.y, b.y),
                     fmaxf(a.z, b.z), fmaxf(a.w, b.w));
}

// ---------------- K0: transpose W (CO x TC) -> WT (TC x CO) ----------------
// Tiny (256 KiB); scattered reads are absorbed by L2.
__global__ void k0_transpose(const float* __restrict__ W, float* __restrict__ WT) {
  int k = blockIdx.x;      // 0..TC-1
  int c = threadIdx.x;     // 0..CO-1
  WT[(size_t)k * CO + c] = W[(size_t)c * TC + k];
}

// ---------------- K1: gather+max+concat + GEMM + bias + partial BN stats ---
__global__ __launch_bounds__(256, 1)
void k1_fused(const float* __restrict__ x, const int* __restrict__ eidx,
              const float* __restrict__ WT, const float* __restrict__ bias,
              float* __restrict__ y, double* __restrict__ stats)
{
  __shared__ __align__(16) float hs[TM][LDH];       // 66560 B
  __shared__ __align__(16) float wl[2][BK][CO];     // 65536 B (double buffer)
  __shared__ __align__(16) int   ids[TM * K_];      // 4096 B

  const int tid = threadIdx.x;
  const long long row0 = (long long)blockIdx.x * TM;   // tiles never cross batches (N%TM==0)
  const int batch = (int)(row0 / N_);
  const float* __restrict__ xb = x + (size_t)batch * N_ * C_;

  // stage edge indices for the tile (64 nodes x 16 = 1024 ints)
  {
    const int4* src = (const int4*)(eidx + row0 * K_);
    ((int4*)ids)[tid] = src[tid];
  }
  __syncthreads();

  // build h tile: h[m][0:128]=x, h[m][128:256]=max_k(neigh)-x
  #pragma unroll
  for (int it = 0; it < (TM * (C_ / 4)) / 256; ++it) {   // 8 iters
    int w = it * 256 + tid;
    int m = w >> 5;             // node within tile (2 nodes per wave)
    int ch = (w & 31) << 2;     // channel offset (float4 granules)
    float4 xv = *(const float4*)(x + (row0 + m) * (long long)C_ + ch);
    float4 mx = make_float4(-INFINITY, -INFINITY, -INFINITY, -INFINITY);
    #pragma unroll
    for (int j = 0; j < K_; ++j) {
      int nb = ids[m * K_ + j];                     // broadcast within half-wave
      float4 v = *(const float4*)(xb + (size_t)nb * C_ + ch);
      mx = f4max(mx, v);
    }
    *(float4*)&hs[m][ch] = xv;
    *(float4*)&hs[m][C_ + ch] = make_float4(mx.x - xv.x, mx.y - xv.y,
                                            mx.z - xv.z, mx.w - xv.w);
  }

  // double-buffered W staging (WT rows are contiguous -> flat 32 KiB copy)
  auto stage = [&](int buf, int k0) {
    const float4* src = (const float4*)(WT + (size_t)k0 * CO);
    float4* dst = (float4*)wl[buf];
    #pragma unroll
    for (int t = 0; t < 8; ++t) dst[t * 256 + tid] = src[t * 256 + tid];
  };
  stage(0, 0);

  const int tm = tid >> 4;    // 0..15 -> 4 nodes each
  const int tn = tid & 15;    // 0..15 -> 16 couts as 4 contiguous quads
  float acc[4][4][4] = {};    // [node][quad][elem]

  int cur = 0;
  #pragma unroll 1
  for (int cch = 0; cch < TC / BK; ++cch) {   // 8 chunks
    __syncthreads();                          // staging of `cur` visible to all
    if (cch < TC / BK - 1) stage(cur ^ 1, (cch + 1) * BK);
    #pragma unroll
    for (int kk = 0; kk < BK; kk += 4) {
      float4 hv[4];
      #pragma unroll
      for (int i = 0; i < 4; ++i)
        hv[i] = *(const float4*)&hs[tm * 4 + i][cch * BK + kk];
      #pragma unroll
      for (int jj = 0; jj < 4; ++jj) {
        #pragma unroll
        for (int kq = 0; kq < 4; ++kq) {
          float4 wv = *(const float4*)&wl[cur][kk + kq][jj * 64 + tn * 4];
          #pragma unroll
          for (int i = 0; i < 4; ++i) {
            float hvi = ((const float*)&hv[i])[kq];
            acc[i][jj][0] = fmaf(hvi, wv.x, acc[i][jj][0]);
            acc[i][jj][1] = fmaf(hvi, wv.y, acc[i][jj][1]);
            acc[i][jj][2] = fmaf(hvi, wv.z, acc[i][jj][2]);
            acc[i][jj][3] = fmaf(hvi, wv.w, acc[i][jj][3]);
          }
        }
      }
    }
    cur ^= 1;
  }

  // epilogue: bias, write y, accumulate local per-channel stats
  float ls[4][4] = {};
  float lq[4][4] = {};
  #pragma unroll
  for (int jj = 0; jj < 4; ++jj) {
    float4 bb = *(const float4*)&bias[jj * 64 + tn * 4];
    #pragma unroll
    for (int i = 0; i < 4; ++i) {
      float4 v;
      v.x = acc[i][jj][0] + bb.x;
      v.y = acc[i][jj][1] + bb.y;
      v.z = acc[i][jj][2] + bb.z;
      v.w = acc[i][jj][3] + bb.w;
      *(float4*)(y + (row0 + tm * 4 + i) * (long long)CO + jj * 64 + tn * 4) = v;
      ls[jj][0] += v.x;       ls[jj][1] += v.y;
      ls[jj][2] += v.z;       ls[jj][3] += v.w;
      lq[jj][0] += v.x * v.x; lq[jj][1] += v.y * v.y;
      lq[jj][2] += v.z * v.z; lq[jj][3] += v.w * v.w;
    }
  }

  // block-level reduce over tm via LDS (reuse wl), then one double atomic per channel
  float* red = (float*)wl;    // red[16][512]
  __syncthreads();
  #pragma unroll
  for (int jj = 0; jj < 4; ++jj) {
    #pragma unroll
    for (int j = 0; j < 4; ++j) {
      int col = jj * 64 + tn * 4 + j;
      red[tm * 512 + col] = ls[jj][j];
      red[tm * 512 + 256 + col] = lq[jj][j];
    }
  }
  __syncthreads();
  {
    float s = 0.f, q = 0.f;
    #pragma unroll
    for (int t = 0; t < 16; ++t) {
      s += red[t * 512 + tid];
      q += red[t * 512 + 256 + tid];
    }
    atomicAdd(&stats[tid], (double)s);
    atomicAdd(&stats[256 + tid], (double)q);
  }
}

// ---------------- K2: finalize BN scale/shift ------------------------------
__global__ void k2_stats(const double* __restrict__ stats,
                         const float* __restrict__ gamma,
                         const float* __restrict__ beta,
                         float* __restrict__ ss)
{
  int c = threadIdx.x;
  double mean = stats[c] * (1.0 / M_);
  double var  = stats[256 + c] * (1.0 / M_) - mean * mean;
  double scale = (double)gamma[c] / sqrt(var + 1e-5);
  ss[c]        = (float)scale;
  ss[256 + c]  = (float)((double)beta[c] - mean * scale);
}

// ---------------- K3: in-place BN + exact GELU -----------------------------
__global__ __launch_bounds__(256)
void k3_bn_gelu(float* __restrict__ y, const float* __restrict__ ss)
{
  __shared__ float s_sc[CO], s_sh[CO];
  s_sc[threadIdx.x] = ss[threadIdx.x];
  s_sh[threadIdx.x] = ss[256 + threadIdx.x];
  __syncthreads();
  const float inv_sqrt2 = 0.70710678118654752440f;
  size_t i = (size_t)blockIdx.x * blockDim.x + threadIdx.x;
  const size_t stride = (size_t)gridDim.x * blockDim.x;
  const size_t total = (size_t)M_ * CO / 4;   // 8388608 float4s
  float4* y4 = (float4*)y;
  for (; i < total; i += stride) {
    float4 v = y4[i];
    int c4 = (int)(i & (CO / 4 - 1)) * 4;   // channel base of this float4
    float4 r;
    { float u = v.x * s_sc[c4 + 0] + s_sh[c4 + 0]; r.x = 0.5f * u * (1.f + erff(u * inv_sqrt2)); }
    { float u = v.y * s_sc[c4 + 1] + s_sh[c4 + 1]; r.y = 0.5f * u * (1.f + erff(u * inv_sqrt2)); }
    { float u = v.z * s_sc[c4 + 2] + s_sh[c4 + 2]; r.z = 0.5f * u * (1.f + erff(u * inv_sqrt2)); }
    { float u = v.w * s_sc[c4 + 3] + s_sh[c4 + 3]; r.w = 0.5f * u * (1.f + erff(u * inv_sqrt2)); }
    y4[i] = r;
  }
}

// ---------------- launcher -------------------------------------------------
extern "C" void kernel_launch(void* const* d_in, const int* in_sizes, int n_in,
                              void* d_out, int out_size, void* d_ws, size_t ws_size,
                              hipStream_t stream)
{
  const float* x     = (const float*)d_in[0];
  const int*   eidx  = (const int*)d_in[1];
  const float* W     = (const float*)d_in[2];
  const float* bias  = (const float*)d_in[3];
  const float* gamma = (const float*)d_in[4];
  const float* beta  = (const float*)d_in[5];
  float* y = (float*)d_out;

  char* ws = (char*)d_ws;
  float*  WT    = (float*)ws;                        // 256 KiB
  double* stats = (double*)(ws + 262144);            // 4 KiB (must be zeroed)
  float*  ss    = (float*)(ws + 262144 + 4096);      // 2 KiB

  hipMemsetAsync(stats, 0, 512 * sizeof(double), stream);
  k0_transpose<<<TC, CO, 0, stream>>>(W, WT);
  k1_fused<<<M_ / TM, 256, 0, stream>>>(x, eidx, WT, bias, y, stats);
  k2_stats<<<1, CO, 0, stream>>>(stats, gamma, beta, ss);
  k3_bn_gelu<<<2048, 256, 0, stream>>>(y, ss);
}

// Round 6
// 324.804 us; speedup vs baseline: 1.7039x; 1.7039x over previous
//
#include <hip/hip_runtime.h>
#include <math.h>

constexpr int B_ = 8;
constexpr int N_ = 16384;
constexpr int C_ = 128;    // input channels
constexpr int K_ = 16;     // neighbors
constexpr int CO = 256;    // output channels
constexpr int TC = 256;    // 2*C
constexpr int M_ = B_ * N_;        // 131072 rows
constexpr int TM = 64;             // nodes per block
constexpr int NB = M_ / TM;        // 2048 blocks
constexpr int NCHUNK = 8;          // K chunks of 32

typedef _Float16 h8 __attribute__((ext_vector_type(8)));
typedef float f4 __attribute__((ext_vector_type(4)));

__device__ __forceinline__ float4 f4max(float4 a, float4 b) {
  return make_float4(fmaxf(a.x, b.x), fmaxf(a.y, b.y),
                     fmaxf(a.z, b.z), fmaxf(a.w, b.w));
}

__device__ __forceinline__ ushort4 pack_h4(float4 v) {
  union { _Float16 h[4]; ushort4 u; } cv;
  cv.h[0] = (_Float16)v.x; cv.h[1] = (_Float16)v.y;
  cv.h[2] = (_Float16)v.z; cv.h[3] = (_Float16)v.w;
  return cv.u;
}

// ---------------- K0: W (CO x TC fp32) -> fp16, B-fragment-linear layout ---
// Wf[kk][nt][(c15 + 16*go)][8] halfs; wave frag read = 16B/lane, 1KB/wave.
__global__ void k0_prep(const float* __restrict__ W, _Float16* __restrict__ Wf) {
  int g = blockIdx.x * 256 + threadIdx.x;   // 0..8191 (cout, k-octet) pairs
  int cout = g >> 5;
  int G = g & 31;                           // k-octet 0..31
  int kk = G >> 2, go = G & 3;
  int nt = cout >> 4, c15 = cout & 15;
  const float* src = W + (size_t)cout * TC + G * 8;
  _Float16* dst = Wf + kk * 8192 + nt * 512 + (c15 + 16 * go) * 8;
  #pragma unroll
  for (int j = 0; j < 8; ++j) dst[j] = (_Float16)src[j];
}

// ---------------- K1: gather+max -> fp16 MFMA GEMM + bias + BN partials ----
// B-fragments read straight from global Wf (L2-hot); no K-loop barriers.
__global__ __launch_bounds__(256, 3)
void k1_fused(const float* __restrict__ x, const int* __restrict__ eidx,
              const _Float16* __restrict__ Wf, const float* __restrict__ bias,
              float* __restrict__ y, double* __restrict__ stats)
{
  __shared__ __align__(16) _Float16 hsf[TM * TC];     // 32 KB, frag-linear + XOR
  __shared__ __align__(16) int ids[TM * K_];          // 4 KB

  const int tid = threadIdx.x;
  const int wave = tid >> 6;
  const int lane = tid & 63;
  const int batch = blockIdx.x & 7;    // batch -> XCD (round-robin dispatch)
  const int tile = blockIdx.x >> 3;
  const long long row0 = (long long)batch * N_ + (long long)tile * TM;
  const float* __restrict__ xb = x + (size_t)batch * N_ * C_;

  // stage edge ids (64 nodes x 16 = 1024 ints)
  ((int4*)ids)[tid] = ((const int4*)(eidx + row0 * K_))[tid];
  __syncthreads();

  // build h tile: frag element h[m][k] -> byte (m>>4)*8192 + (k>>3)*256 +
  // (m&15)*16 + (k&7)*2, XOR-swizzled (involution, both sides).
  #pragma unroll
  for (int it = 0; it < 8; ++it) {
    int w = it * 256 + tid;
    int m = w >> 5;                 // node in tile
    int cq = (w & 31) << 2;         // channel 0..124 step 4
    float4 xv = *(const float4*)(x + (row0 + m) * (size_t)C_ + cq);
    float4 mx = make_float4(-INFINITY, -INFINITY, -INFINITY, -INFINITY);
    #pragma unroll
    for (int j = 0; j < K_; ++j) {
      int nb = ids[m * K_ + j];
      mx = f4max(mx, *(const float4*)(xb + (size_t)nb * C_ + cq));
    }
    int a0 = ((m >> 4) << 13) | ((cq >> 3) << 8) | ((m & 15) << 4) | ((cq & 4) << 1);
    a0 ^= ((a0 >> 8) & 7) << 4;
    *(ushort4*)((char*)hsf + a0) = pack_h4(xv);
    float4 dv = make_float4(mx.x - xv.x, mx.y - xv.y, mx.z - xv.z, mx.w - xv.w);
    int c2 = 128 + cq;
    int a1 = ((m >> 4) << 13) | ((c2 >> 3) << 8) | ((m & 15) << 4) | ((c2 & 4) << 1);
    a1 ^= ((a1 >> 8) & 7) << 4;
    *(ushort4*)((char*)hsf + a1) = pack_h4(dv);
  }
  __syncthreads();

  // K loop: wave tile = 64 nodes x 64 couts; hsf is read-only from here on.
  f4 acc[4][4] = {};
  #pragma unroll
  for (int kk = 0; kk < NCHUNK; ++kk) {
    h8 af[4], bf[4];
    #pragma unroll
    for (int nt = 0; nt < 4; ++nt)
      bf[nt] = *(const h8*)((const char*)Wf + (kk << 14) + (wave << 12) + (nt << 10) + (lane << 4));
    #pragma unroll
    for (int mt = 0; mt < 4; ++mt) {
      int off = (mt << 13) + (kk << 10) + lane * 16;
      off ^= ((off >> 8) & 7) << 4;
      af[mt] = *(const h8*)((const char*)hsf + off);
    }
    #pragma unroll
    for (int mt = 0; mt < 4; ++mt)
      #pragma unroll
      for (int nt = 0; nt < 4; ++nt)
        acc[mt][nt] = __builtin_amdgcn_mfma_f32_16x16x32_f16(af[mt], bf[nt], acc[mt][nt], 0, 0, 0);
  }

  // epilogue: bias, y write, per-channel stats (wave shfl + double atomics)
  const int c15 = lane & 15;
  const int rg = lane >> 4;     // C/D row = rg*4 + r (verified mapping m89/m91)
  float s4[4] = {0.f, 0.f, 0.f, 0.f};
  float q4[4] = {0.f, 0.f, 0.f, 0.f};
  #pragma unroll
  for (int nt = 0; nt < 4; ++nt) {
    int col = (wave << 6) + (nt << 4) + c15;
    float bb = bias[col];
    #pragma unroll
    for (int mt = 0; mt < 4; ++mt) {
      #pragma unroll
      for (int r = 0; r < 4; ++r) {
        float v = acc[mt][nt][r] + bb;
        long long row = row0 + (mt << 4) + (rg << 2) + r;
        y[row * CO + col] = v;
        s4[nt] += v;
        q4[nt] += v * v;
      }
    }
  }
  #pragma unroll
  for (int nt = 0; nt < 4; ++nt) {
    s4[nt] += __shfl_xor(s4[nt], 16, 64);
    s4[nt] += __shfl_xor(s4[nt], 32, 64);
    q4[nt] += __shfl_xor(q4[nt], 16, 64);
    q4[nt] += __shfl_xor(q4[nt], 32, 64);
  }
  if (lane < 16) {
    #pragma unroll
    for (int nt = 0; nt < 4; ++nt) {
      int col = (wave << 6) + (nt << 4) + c15;
      atomicAdd(&stats[col], (double)s4[nt]);
      atomicAdd(&stats[col + 256], (double)q4[nt]);
    }
  }
}

// ---------------- K2: finalize BN scale/shift ------------------------------
__global__ void k2_stats(const double* __restrict__ stats,
                         const float* __restrict__ gamma,
                         const float* __restrict__ beta,
                         float* __restrict__ ss) {
  int c = threadIdx.x;
  double mean = stats[c] * (1.0 / M_);
  double var  = stats[256 + c] * (1.0 / M_) - mean * mean;
  double scale = (double)gamma[c] / sqrt(var + 1e-5);
  ss[c]       = (float)scale;
  ss[256 + c] = (float)((double)beta[c] - mean * scale);
}

// ---------------- K3: in-place BN + exact GELU -----------------------------
__global__ __launch_bounds__(256)
void k3_bn_gelu(float* __restrict__ y, const float* __restrict__ ss) {
  __shared__ float s_sc[CO], s_sh[CO];
  s_sc[threadIdx.x] = ss[threadIdx.x];
  s_sh[threadIdx.x] = ss[256 + threadIdx.x];
  __syncthreads();
  const float inv_sqrt2 = 0.70710678118654752440f;
  size_t i = (size_t)blockIdx.x * blockDim.x + threadIdx.x;
  const size_t stride = (size_t)gridDim.x * blockDim.x;
  const size_t total = (size_t)M_ * CO / 4;
  float4* y4 = (float4*)y;
  for (; i < total; i += stride) {
    float4 v = y4[i];
    int c4 = (int)(i & (CO / 4 - 1)) * 4;
    float4 r;
    { float u = v.x * s_sc[c4 + 0] + s_sh[c4 + 0]; r.x = 0.5f * u * (1.f + erff(u * inv_sqrt2)); }
    { float u = v.y * s_sc[c4 + 1] + s_sh[c4 + 1]; r.y = 0.5f * u * (1.f + erff(u * inv_sqrt2)); }
    { float u = v.z * s_sc[c4 + 2] + s_sh[c4 + 2]; r.z = 0.5f * u * (1.f + erff(u * inv_sqrt2)); }
    { float u = v.w * s_sc[c4 + 3] + s_sh[c4 + 3]; r.w = 0.5f * u * (1.f + erff(u * inv_sqrt2)); }
    y4[i] = r;
  }
}

// ---------------- launcher -------------------------------------------------
extern "C" void kernel_launch(void* const* d_in, const int* in_sizes, int n_in,
                              void* d_out, int out_size, void* d_ws, size_t ws_size,
                              hipStream_t stream)
{
  const float* x     = (const float*)d_in[0];
  const int*   eidx  = (const int*)d_in[1];
  const float* W     = (const float*)d_in[2];
  const float* bias  = (const float*)d_in[3];
  const float* gamma = (const float*)d_in[4];
  const float* beta  = (const float*)d_in[5];
  float* y = (float*)d_out;
  char* ws = (char*)d_ws;

  _Float16* Wf    = (_Float16*)ws;                    // 128 KB
  double*   stats = (double*)(ws + 131072);           // 4 KB (zeroed each call)
  float*    ss    = (float*)(ws + 131072 + 4096);     // 2 KB

  hipMemsetAsync(stats, 0, 512 * sizeof(double), stream);
  k0_prep<<<32, 256, 0, stream>>>(W, Wf);
  k1_fused<<<NB, 256, 0, stream>>>(x, eidx, Wf, bias, y, stats);
  k2_stats<<<1, 256, 0, stream>>>(stats, gamma, beta, ss);
  k3_bn_gelu<<<2048, 256, 0, stream>>>(y, ss);
}

// Round 11
// 296.634 us; speedup vs baseline: 1.8657x; 1.0950x over previous
//
#include <hip/hip_runtime.h>
#include <math.h>

constexpr int B_ = 8;
constexpr int N_ = 16384;
constexpr int C_ = 128;    // input channels
constexpr int K_ = 16;     // neighbors
constexpr int CO = 256;    // output channels
constexpr int TC = 256;    // 2*C
constexpr int M_ = B_ * N_;        // 131072 rows
constexpr int TM = 64;             // nodes per block
constexpr int NB = M_ / TM;        // 2048 blocks
constexpr int NCHUNK = 8;          // K chunks of 32

typedef _Float16 h8 __attribute__((ext_vector_type(8)));
typedef float f4 __attribute__((ext_vector_type(4)));

__device__ __forceinline__ float4 f4max(float4 a, float4 b) {
  return make_float4(fmaxf(a.x, b.x), fmaxf(a.y, b.y),
                     fmaxf(a.z, b.z), fmaxf(a.w, b.w));
}

__device__ __forceinline__ ushort4 pack_h4(float4 v) {
  union { _Float16 h[4]; ushort4 u; } cv;
  cv.h[0] = (_Float16)v.x; cv.h[1] = (_Float16)v.y;
  cv.h[2] = (_Float16)v.z; cv.h[3] = (_Float16)v.w;
  return cv.u;
}

// packed fp16 max / sub on 8 halfs carried in a uint4 (plain _Float16 ops —
// no __half2 intrinsics; ROCm 7.2 lacks a viable __hmax2 overload here)
__device__ __forceinline__ uint4 hmax4(uint4 a, uint4 b) {
  union U { uint4 u; _Float16 h[8]; } ua, ub, r;
  ua.u = a; ub.u = b;
  #pragma unroll
  for (int i = 0; i < 8; ++i) r.h[i] = ua.h[i] > ub.h[i] ? ua.h[i] : ub.h[i];
  return r.u;
}

__device__ __forceinline__ uint4 hsub4(uint4 a, uint4 b) {   // a - b
  union U { uint4 u; _Float16 h[8]; } ua, ub, r;
  ua.u = a; ub.u = b;
  #pragma unroll
  for (int i = 0; i < 8; ++i) r.h[i] = ua.h[i] - ub.h[i];
  return r.u;
}

// fast exact-GELU: erf via A&S 7.1.26 (|err| <= 1.5e-7), branch-free
__device__ __forceinline__ float gelu_f(float u) {
  float z = fabsf(u) * 0.70710678118654752f;
  float t = 1.0f / (1.0f + 0.3275911f * z);
  float p = t * (0.254829592f + t * (-0.284496736f + t * (1.421413741f +
            t * (-1.453152027f + t * 1.061405429f))));
  float erfz = 1.0f - p * __expf(-z * z);
  erfz = copysignf(erfz, u);
  return 0.5f * u * (1.0f + erfz);
}

// ---------------- K0: W (CO x TC fp32) -> fp16, B-fragment-linear layout ---
__global__ void k0_prep(const float* __restrict__ W, _Float16* __restrict__ Wf) {
  int g = blockIdx.x * 256 + threadIdx.x;   // 0..8191 (cout, k-octet) pairs
  int cout = g >> 5;
  int G = g & 31;                           // k-octet 0..31
  int kk = G >> 2, go = G & 3;
  int nt = cout >> 4, c15 = cout & 15;
  const float* src = W + (size_t)cout * TC + G * 8;
  _Float16* dst = Wf + kk * 8192 + nt * 512 + (c15 + 16 * go) * 8;
  #pragma unroll
  for (int j = 0; j < 8; ++j) dst[j] = (_Float16)src[j];
}

// ---------------- K0b: x (fp32) -> xh (fp16), 4 MiB/batch = one XCD L2 ----
__global__ __launch_bounds__(256)
void k0b_cvt(const float* __restrict__ x, _Float16* __restrict__ xh) {
  const size_t total = (size_t)M_ * C_ / 4;   // float4 groups
  const size_t stride = (size_t)gridDim.x * 256;
  for (size_t i = (size_t)blockIdx.x * 256 + threadIdx.x; i < total; i += stride) {
    float4 a = ((const float4*)x)[i];
    ((ushort4*)xh)[i] = pack_h4(a);
  }
}

// ---------------- K1: gather+max -> fp16 MFMA GEMM + bias + BN partials ----
// B-fragments read straight from global Wf (L2-hot); no K-loop barriers.
template <int FP16>
__global__ __launch_bounds__(256, 4)
void k1_fused(const float* __restrict__ x, const int* __restrict__ eidx,
              const _Float16* __restrict__ Wf, const float* __restrict__ bias,
              float* __restrict__ y, double* __restrict__ stats,
              const _Float16* __restrict__ xh)
{
  __shared__ __align__(16) _Float16 hsf[TM * TC];     // 32 KB, frag-linear + XOR
  __shared__ __align__(16) int ids[TM * K_];          // 4 KB

  const int tid = threadIdx.x;
  const int wave = tid >> 6;
  const int lane = tid & 63;
  const int batch = blockIdx.x & 7;    // batch -> XCD (round-robin dispatch)
  const int tile = blockIdx.x >> 3;
  const long long row0 = (long long)batch * N_ + (long long)tile * TM;

  // stage edge ids (64 nodes x 16 = 1024 ints)
  ((int4*)ids)[tid] = ((const int4*)(eidx + row0 * K_))[tid];
  __syncthreads();

  // build h tile; linear addr of h[m][k] = (m>>4)<<13 | (k>>3)<<8 |
  // (m&15)<<4 | (k&7)<<1, then XOR involution a ^= ((a>>8)&7)<<4 (both sides).
  if constexpr (FP16) {
    const _Float16* __restrict__ xbh = xh + (size_t)batch * N_ * C_;
    #pragma unroll
    for (int it = 0; it < 4; ++it) {
      int w = it * 256 + tid;
      int m = w >> 4;                 // node in tile (16 threads/node)
      int ch8 = (w & 15) << 3;        // 8-channel granule
      uint4 xv = *(const uint4*)(xh + (row0 + m) * (size_t)C_ + ch8);
      uint4 mx = *(const uint4*)(xbh + (size_t)ids[m * K_] * C_ + ch8);
      #pragma unroll
      for (int j = 1; j < K_; ++j) {
        int nb = ids[m * K_ + j];
        mx = hmax4(mx, *(const uint4*)(xbh + (size_t)nb * C_ + ch8));
      }
      uint4 dv = hsub4(mx, xv);
      int a0 = ((m >> 4) << 13) | ((ch8 >> 3) << 8) | ((m & 15) << 4);
      a0 ^= ((a0 >> 8) & 7) << 4;
      *(uint4*)((char*)hsf + a0) = xv;
      int c2 = 128 + ch8;
      int a1 = ((m >> 4) << 13) | ((c2 >> 3) << 8) | ((m & 15) << 4);
      a1 ^= ((a1 >> 8) & 7) << 4;
      *(uint4*)((char*)hsf + a1) = dv;
    }
  } else {
    const float* __restrict__ xb = x + (size_t)batch * N_ * C_;
    #pragma unroll
    for (int it = 0; it < 8; ++it) {
      int w = it * 256 + tid;
      int m = w >> 5;                 // node in tile
      int cq = (w & 31) << 2;         // channel 0..124 step 4
      float4 xv = *(const float4*)(x + (row0 + m) * (size_t)C_ + cq);
      float4 mx = make_float4(-INFINITY, -INFINITY, -INFINITY, -INFINITY);
      #pragma unroll
      for (int j = 0; j < K_; ++j) {
        int nb = ids[m * K_ + j];
        mx = f4max(mx, *(const float4*)(xb + (size_t)nb * C_ + cq));
      }
      int a0 = ((m >> 4) << 13) | ((cq >> 3) << 8) | ((m & 15) << 4) | ((cq & 4) << 1);
      a0 ^= ((a0 >> 8) & 7) << 4;
      *(ushort4*)((char*)hsf + a0) = pack_h4(xv);
      float4 dv = make_float4(mx.x - xv.x, mx.y - xv.y, mx.z - xv.z, mx.w - xv.w);
      int c2 = 128 + cq;
      int a1 = ((m >> 4) << 13) | ((c2 >> 3) << 8) | ((m & 15) << 4) | ((cq & 4) << 1);
      a1 ^= ((a1 >> 8) & 7) << 4;
      *(ushort4*)((char*)hsf + a1) = pack_h4(dv);
    }
  }
  __syncthreads();

  // K loop: wave tile = 64 nodes x 64 couts; hsf is read-only from here on.
  f4 acc[4][4] = {};
  #pragma unroll
  for (int kk = 0; kk < NCHUNK; ++kk) {
    h8 af[4], bf[4];
    #pragma unroll
    for (int nt = 0; nt < 4; ++nt)
      bf[nt] = *(const h8*)((const char*)Wf + (kk << 14) + (wave << 12) + (nt << 10) + (lane << 4));
    #pragma unroll
    for (int mt = 0; mt < 4; ++mt) {
      int off = (mt << 13) + (kk << 10) + lane * 16;
      off ^= ((off >> 8) & 7) << 4;
      af[mt] = *(const h8*)((const char*)hsf + off);
    }
    #pragma unroll
    for (int mt = 0; mt < 4; ++mt)
      #pragma unroll
      for (int nt = 0; nt < 4; ++nt)
        acc[mt][nt] = __builtin_amdgcn_mfma_f32_16x16x32_f16(af[mt], bf[nt], acc[mt][nt], 0, 0, 0);
  }

  // epilogue: bias, y write, per-channel stats (wave shfl + double atomics)
  const int c15 = lane & 15;
  const int rg = lane >> 4;     // C/D row = rg*4 + r
  float s4[4] = {0.f, 0.f, 0.f, 0.f};
  float q4[4] = {0.f, 0.f, 0.f, 0.f};
  #pragma unroll
  for (int nt = 0; nt < 4; ++nt) {
    int col = (wave << 6) + (nt << 4) + c15;
    float bb = bias[col];
    #pragma unroll
    for (int mt = 0; mt < 4; ++mt) {
      #pragma unroll
      for (int r = 0; r < 4; ++r) {
        float v = acc[mt][nt][r] + bb;
        long long row = row0 + (mt << 4) + (rg << 2) + r;
        y[row * CO + col] = v;
        s4[nt] += v;
        q4[nt] += v * v;
      }
    }
  }
  #pragma unroll
  for (int nt = 0; nt < 4; ++nt) {
    s4[nt] += __shfl_xor(s4[nt], 16, 64);
    s4[nt] += __shfl_xor(s4[nt], 32, 64);
    q4[nt] += __shfl_xor(q4[nt], 16, 64);
    q4[nt] += __shfl_xor(q4[nt], 32, 64);
  }
  if (lane < 16) {
    #pragma unroll
    for (int nt = 0; nt < 4; ++nt) {
      int col = (wave << 6) + (nt << 4) + c15;
      atomicAdd(&stats[col], (double)s4[nt]);
      atomicAdd(&stats[col + 256], (double)q4[nt]);
    }
  }
}

// ---------------- K2: finalize BN scale/shift ------------------------------
__global__ void k2_stats(const double* __restrict__ stats,
                         const float* __restrict__ gamma,
                         const float* __restrict__ beta,
                         float* __restrict__ ss) {
  int c = threadIdx.x;
  double mean = stats[c] * (1.0 / M_);
  double var  = stats[256 + c] * (1.0 / M_) - mean * mean;
  double scale = (double)gamma[c] / sqrt(var + 1e-5);
  ss[c]       = (float)scale;
  ss[256 + c] = (float)((double)beta[c] - mean * scale);
}

// ---------------- K3: in-place BN + fast exact GELU ------------------------
__global__ __launch_bounds__(256)
void k3_bn_gelu(float* __restrict__ y, const float* __restrict__ ss) {
  size_t i = (size_t)blockIdx.x * blockDim.x + threadIdx.x;
  const size_t stride = (size_t)gridDim.x * blockDim.x;   // multiple of 64
  const size_t total = (size_t)M_ * CO / 4;
  // channel group is loop-invariant per thread (stride % 64 == 0)
  int c4 = (int)(i & (CO / 4 - 1)) * 4;
  float4 sc = *(const float4*)(ss + c4);
  float4 sh = *(const float4*)(ss + 256 + c4);
  float4* y4 = (float4*)y;
  for (; i < total; i += stride) {
    float4 v = y4[i];
    float4 r;
    r.x = gelu_f(v.x * sc.x + sh.x);
    r.y = gelu_f(v.y * sc.y + sh.y);
    r.z = gelu_f(v.z * sc.z + sh.z);
    r.w = gelu_f(v.w * sc.w + sh.w);
    y4[i] = r;
  }
}

// ---------------- launcher -------------------------------------------------
extern "C" void kernel_launch(void* const* d_in, const int* in_sizes, int n_in,
                              void* d_out, int out_size, void* d_ws, size_t ws_size,
                              hipStream_t stream)
{
  const float* x     = (const float*)d_in[0];
  const int*   eidx  = (const int*)d_in[1];
  const float* W     = (const float*)d_in[2];
  const float* bias  = (const float*)d_in[3];
  const float* gamma = (const float*)d_in[4];
  const float* beta  = (const float*)d_in[5];
  float* y = (float*)d_out;
  char* ws = (char*)d_ws;

  _Float16* Wf    = (_Float16*)ws;                    // 128 KB
  double*   stats = (double*)(ws + 131072);           // 4 KB (zeroed each call)
  float*    ss    = (float*)(ws + 131072 + 4096);     // 2 KB
  _Float16* xh    = (_Float16*)(ws + (1 << 20));      // 32 MiB (fp16 path)
  const size_t ws_needed = (1 << 20) + (size_t)M_ * C_ * 2;
  const bool fp16path = ws_size >= ws_needed;         // constant per session

  (void)hipMemsetAsync(stats, 0, 512 * sizeof(double), stream);
  k0_prep<<<32, 256, 0, stream>>>(W, Wf);
  if (fp16path) {
    k0b_cvt<<<2048, 256, 0, stream>>>(x, xh);
    k1_fused<1><<<NB, 256, 0, stream>>>(x, eidx, Wf, bias, y, stats, xh);
  } else {
    k1_fused<0><<<NB, 256, 0, stream>>>(x, eidx, Wf, bias, y, stats, nullptr);
  }
  k2_stats<<<1, 256, 0, stream>>>(stats, gamma, beta, ss);
  k3_bn_gelu<<<2048, 256, 0, stream>>>(y, ss);
}

// Round 12
// 289.479 us; speedup vs baseline: 1.9118x; 1.0247x over previous
//
#include <hip/hip_runtime.h>
#include <math.h>

constexpr int B_ = 8;
constexpr int N_ = 16384;
constexpr int C_ = 128;    // input channels
constexpr int K_ = 16;     // neighbors
constexpr int CO = 256;    // output channels
constexpr int TC = 256;    // 2*C
constexpr int M_ = B_ * N_;        // 131072 rows
constexpr int TM = 64;             // nodes per block
constexpr int NB = M_ / TM;        // 2048 blocks
constexpr int NCHUNK = 8;          // K chunks of 32

typedef _Float16 h8 __attribute__((ext_vector_type(8)));
typedef float f4 __attribute__((ext_vector_type(4)));

__device__ __forceinline__ float4 f4max(float4 a, float4 b) {
  return make_float4(fmaxf(a.x, b.x), fmaxf(a.y, b.y),
                     fmaxf(a.z, b.z), fmaxf(a.w, b.w));
}

__device__ __forceinline__ ushort4 pack_h4(float4 v) {
  union { _Float16 h[4]; ushort4 u; } cv;
  cv.h[0] = (_Float16)v.x; cv.h[1] = (_Float16)v.y;
  cv.h[2] = (_Float16)v.z; cv.h[3] = (_Float16)v.w;
  return cv.u;
}

// packed fp16 max / sub on 8 halfs in a uint4 (plain _Float16 ops)
__device__ __forceinline__ uint4 hmax4(uint4 a, uint4 b) {
  union U { uint4 u; _Float16 h[8]; } ua, ub, r;
  ua.u = a; ub.u = b;
  #pragma unroll
  for (int i = 0; i < 8; ++i) r.h[i] = ua.h[i] > ub.h[i] ? ua.h[i] : ub.h[i];
  return r.u;
}

__device__ __forceinline__ uint4 hsub4(uint4 a, uint4 b) {   // a - b
  union U { uint4 u; _Float16 h[8]; } ua, ub, r;
  ua.u = a; ub.u = b;
  #pragma unroll
  for (int i = 0; i < 8; ++i) r.h[i] = ua.h[i] - ub.h[i];
  return r.u;
}

// fast exact-GELU: erf via A&S 7.1.26 (|err| <= 1.5e-7), branch-free
__device__ __forceinline__ float gelu_f(float u) {
  float z = fabsf(u) * 0.70710678118654752f;
  float t = 1.0f / (1.0f + 0.3275911f * z);
  float p = t * (0.254829592f + t * (-0.284496736f + t * (1.421413741f +
            t * (-1.453152027f + t * 1.061405429f))));
  float erfz = 1.0f - p * __expf(-z * z);
  erfz = copysignf(erfz, u);
  return 0.5f * u * (1.0f + erfz);
}

// ---------------- kA: W->fp16 frag layout  |  stats zero  |  x->fp16 -------
// blocks 0..31: W prep; block 32: zero stats; blocks 33..2080: x cast.
__global__ __launch_bounds__(256)
void kA_prep(const float* __restrict__ W, _Float16* __restrict__ Wf,
             const float* __restrict__ x, _Float16* __restrict__ xh,
             double* __restrict__ stats)
{
  const int bid = blockIdx.x;
  const int tid = threadIdx.x;
  if (bid < 32) {
    int g = bid * 256 + tid;                // (cout, k-octet) pairs
    int cout = g >> 5;
    int G = g & 31;
    int kk = G >> 2, go = G & 3;
    int nt = cout >> 4, c15 = cout & 15;
    const float* src = W + (size_t)cout * TC + G * 8;
    _Float16* dst = Wf + kk * 8192 + nt * 512 + (c15 + 16 * go) * 8;
    #pragma unroll
    for (int j = 0; j < 8; ++j) dst[j] = (_Float16)src[j];
  } else if (bid == 32) {
    stats[tid] = 0.0;
    stats[256 + tid] = 0.0;
  } else if (xh != nullptr) {
    const size_t total = (size_t)M_ * C_ / 4;      // float4 groups
    const size_t stride = (size_t)2048 * 256;
    for (size_t i = (size_t)(bid - 33) * 256 + tid; i < total; i += stride)
      ((ushort4*)xh)[i] = pack_h4(((const float4*)x)[i]);
  }
}

// ---------------- K1: gather+max -> fp16 MFMA GEMM + bias + BN partials ----
// B-fragments read straight from global Wf (L2-hot); no K-loop barriers.
template <int FP16>
__global__ __launch_bounds__(256, 4)
void k1_fused(const float* __restrict__ x, const int* __restrict__ eidx,
              const _Float16* __restrict__ Wf, const float* __restrict__ bias,
              float* __restrict__ y, double* __restrict__ stats,
              const _Float16* __restrict__ xh)
{
  __shared__ __align__(16) _Float16 hsf[TM * TC];     // 32 KB, frag-linear + XOR
  __shared__ __align__(16) int ids[TM * K_];          // 4 KB

  const int tid = threadIdx.x;
  const int wave = tid >> 6;
  const int lane = tid & 63;
  const int batch = blockIdx.x & 7;    // batch -> XCD (round-robin dispatch)
  const int tile = blockIdx.x >> 3;
  const long long row0 = (long long)batch * N_ + (long long)tile * TM;

  // stage edge ids (64 nodes x 16 = 1024 ints)
  ((int4*)ids)[tid] = ((const int4*)(eidx + row0 * K_))[tid];
  __syncthreads();

  // build h tile; linear addr of h[m][k] = (m>>4)<<13 | (k>>3)<<8 |
  // (m&15)<<4 | (k&7)<<1, then XOR involution a ^= ((a>>8)&7)<<4 (both sides).
  if constexpr (FP16) {
    // 32-bit byte offsets vs wave-uniform base: nb*C_*2 = nb<<8 <= 4 MiB
    const char* __restrict__ xb8 = (const char*)(xh + (size_t)batch * N_ * C_);
    #pragma unroll
    for (int it = 0; it < 4; ++it) {
      int w = it * 256 + tid;
      int m = w >> 4;                 // node in tile (16 threads/node)
      int ch8 = (w & 15) << 3;        // 8-channel granule
      unsigned co = (unsigned)(ch8 << 1);
      unsigned self = ((unsigned)(unsigned long long)(row0 + m) << 8) + co;
      uint4 xv = *(const uint4*)((const char*)xh + self);
      uint4 mx = *(const uint4*)(xb8 + (((unsigned)ids[m * K_] << 8) + co));
      #pragma unroll
      for (int j = 1; j < K_; ++j) {
        unsigned off = ((unsigned)ids[m * K_ + j] << 8) + co;
        mx = hmax4(mx, *(const uint4*)(xb8 + off));
      }
      uint4 dv = hsub4(mx, xv);
      int a0 = ((m >> 4) << 13) | ((ch8 >> 3) << 8) | ((m & 15) << 4);
      a0 ^= ((a0 >> 8) & 7) << 4;
      *(uint4*)((char*)hsf + a0) = xv;
      int c2 = 128 + ch8;
      int a1 = ((m >> 4) << 13) | ((c2 >> 3) << 8) | ((m & 15) << 4);
      a1 ^= ((a1 >> 8) & 7) << 4;
      *(uint4*)((char*)hsf + a1) = dv;
    }
  } else {
    const float* __restrict__ xb = x + (size_t)batch * N_ * C_;
    #pragma unroll
    for (int it = 0; it < 8; ++it) {
      int w = it * 256 + tid;
      int m = w >> 5;                 // node in tile
      int cq = (w & 31) << 2;         // channel 0..124 step 4
      float4 xv = *(const float4*)(x + (row0 + m) * (size_t)C_ + cq);
      float4 mx = make_float4(-INFINITY, -INFINITY, -INFINITY, -INFINITY);
      #pragma unroll
      for (int j = 0; j < K_; ++j) {
        int nb = ids[m * K_ + j];
        mx = f4max(mx, *(const float4*)(xb + (size_t)nb * C_ + cq));
      }
      int a0 = ((m >> 4) << 13) | ((cq >> 3) << 8) | ((m & 15) << 4) | ((cq & 4) << 1);
      a0 ^= ((a0 >> 8) & 7) << 4;
      *(ushort4*)((char*)hsf + a0) = pack_h4(xv);
      float4 dv = make_float4(mx.x - xv.x, mx.y - xv.y, mx.z - xv.z, mx.w - xv.w);
      int c2 = 128 + cq;
      int a1 = ((m >> 4) << 13) | ((c2 >> 3) << 8) | ((m & 15) << 4) | ((cq & 4) << 1);
      a1 ^= ((a1 >> 8) & 7) << 4;
      *(ushort4*)((char*)hsf + a1) = pack_h4(dv);
    }
  }
  __syncthreads();

  // K loop: wave tile = 64 nodes x 64 couts; hsf is read-only from here on.
  f4 acc[4][4] = {};
  #pragma unroll
  for (int kk = 0; kk < NCHUNK; ++kk) {
    h8 af[4], bf[4];
    #pragma unroll
    for (int nt = 0; nt < 4; ++nt)
      bf[nt] = *(const h8*)((const char*)Wf + (kk << 14) + (wave << 12) + (nt << 10) + (lane << 4));
    #pragma unroll
    for (int mt = 0; mt < 4; ++mt) {
      int off = (mt << 13) + (kk << 10) + lane * 16;
      off ^= ((off >> 8) & 7) << 4;
      af[mt] = *(const h8*)((const char*)hsf + off);
    }
    #pragma unroll
    for (int mt = 0; mt < 4; ++mt)
      #pragma unroll
      for (int nt = 0; nt < 4; ++nt)
        acc[mt][nt] = __builtin_amdgcn_mfma_f32_16x16x32_f16(af[mt], bf[nt], acc[mt][nt], 0, 0, 0);
  }

  // epilogue: bias, y write, per-channel stats (wave shfl + double atomics)
  const int c15 = lane & 15;
  const int rg = lane >> 4;     // C/D row = rg*4 + r
  float s4[4] = {0.f, 0.f, 0.f, 0.f};
  float q4[4] = {0.f, 0.f, 0.f, 0.f};
  #pragma unroll
  for (int nt = 0; nt < 4; ++nt) {
    int col = (wave << 6) + (nt << 4) + c15;
    float bb = bias[col];
    #pragma unroll
    for (int mt = 0; mt < 4; ++mt) {
      #pragma unroll
      for (int r = 0; r < 4; ++r) {
        float v = acc[mt][nt][r] + bb;
        long long row = row0 + (mt << 4) + (rg << 2) + r;
        y[row * CO + col] = v;
        s4[nt] += v;
        q4[nt] += v * v;
      }
    }
  }
  #pragma unroll
  for (int nt = 0; nt < 4; ++nt) {
    s4[nt] += __shfl_xor(s4[nt], 16, 64);
    s4[nt] += __shfl_xor(s4[nt], 32, 64);
    q4[nt] += __shfl_xor(q4[nt], 16, 64);
    q4[nt] += __shfl_xor(q4[nt], 32, 64);
  }
  if (lane < 16) {
    #pragma unroll
    for (int nt = 0; nt < 4; ++nt) {
      int col = (wave << 6) + (nt << 4) + c15;
      atomicAdd(&stats[col], (double)s4[nt]);
      atomicAdd(&stats[col + 256], (double)q4[nt]);
    }
  }
}

// ---------------- kB: inline BN finalize + BN + fast GELU (in place) -------
__global__ __launch_bounds__(256)
void kB_bn_gelu(float* __restrict__ y, const double* __restrict__ stats,
                const float* __restrict__ gamma, const float* __restrict__ beta)
{
  // per-thread channel quad is loop-invariant (grid stride % 64 threads == 0)
  const int c4 = (threadIdx.x & 63) * 4;
  float sc[4], sh[4];
  #pragma unroll
  for (int j = 0; j < 4; ++j) {
    int c = c4 + j;
    double mean = stats[c] * (1.0 / M_);
    double var  = stats[256 + c] * (1.0 / M_) - mean * mean;
    double scale = (double)gamma[c] / sqrt(var + 1e-5);
    sc[j] = (float)scale;
    sh[j] = (float)((double)beta[c] - mean * scale);
  }
  size_t i = (size_t)blockIdx.x * blockDim.x + threadIdx.x;
  const size_t stride = (size_t)gridDim.x * blockDim.x;   // multiple of 64
  const size_t total = (size_t)M_ * CO / 4;
  float4* y4 = (float4*)y;
  for (; i < total; i += stride) {
    float4 v = y4[i];
    float4 r;
    r.x = gelu_f(v.x * sc[0] + sh[0]);
    r.y = gelu_f(v.y * sc[1] + sh[1]);
    r.z = gelu_f(v.z * sc[2] + sh[2]);
    r.w = gelu_f(v.w * sc[3] + sh[3]);
    y4[i] = r;
  }
}

// ---------------- launcher -------------------------------------------------
extern "C" void kernel_launch(void* const* d_in, const int* in_sizes, int n_in,
                              void* d_out, int out_size, void* d_ws, size_t ws_size,
                              hipStream_t stream)
{
  const float* x     = (const float*)d_in[0];
  const int*   eidx  = (const int*)d_in[1];
  const float* W     = (const float*)d_in[2];
  const float* bias  = (const float*)d_in[3];
  const float* gamma = (const float*)d_in[4];
  const float* beta  = (const float*)d_in[5];
  float* y = (float*)d_out;
  char* ws = (char*)d_ws;

  _Float16* Wf    = (_Float16*)ws;                    // 128 KB
  double*   stats = (double*)(ws + 131072);           // 4 KB (zeroed by kA)
  _Float16* xh    = (_Float16*)(ws + (1 << 20));      // 32 MiB (fp16 path)
  const size_t ws_needed = (1 << 20) + (size_t)M_ * C_ * 2;
  const bool fp16path = ws_size >= ws_needed;         // constant per session

  kA_prep<<<2081, 256, 0, stream>>>(W, Wf, x, fp16path ? xh : nullptr, stats);
  if (fp16path) {
    k1_fused<1><<<NB, 256, 0, stream>>>(x, eidx, Wf, bias, y, stats, xh);
  } else {
    k1_fused<0><<<NB, 256, 0, stream>>>(x, eidx, Wf, bias, y, stats, nullptr);
  }
  kB_bn_gelu<<<4096, 256, 0, stream>>>(y, stats, gamma, beta);
}